// Round 10
// baseline (1217.743 us; speedup 1.0000x reference)
//
#include <hip/hip_runtime.h>
#include <math.h>

// ---------------------------------------------------------------------------
// KimiDeltaAttention forward, MI355X. Round 9: scan4 = 256 blocks x 1 wave
// (scan2 placement) + async global_load_lds double-buffered chunk pipeline
// with counted s_waitcnt vmcnt(17) (T3/T4), XOR bank-swizzle baked into
// prep's P'/q~/khat/Bd layouts (both-sides, rule #21). GEMMs unchanged.
// Shapes fixed: B=2, T=4096, D=2048, H=16, Dk=Dv=128.
// ---------------------------------------------------------------------------

constexpr int NB = 2, NT = 4096, ND = 2048, NH = 16, DK = 128, DV = 128;
constexpr int MROWS = NB * NT;   // 8192
constexpr int BHN   = NB * NH;   // 32
constexpr int CCH   = 16;        // chunk length
constexpr int NCH   = NT / CCH;  // 256 chunks per sequence

#define DEV static __device__ __forceinline__

typedef __attribute__((ext_vector_type(8))) short short8;   // bf16x8 MFMA frag
typedef __attribute__((ext_vector_type(4))) short short4v;  // bf16x4 MFMA frag
typedef __attribute__((ext_vector_type(4))) float f32x4;    // MFMA acc frag

DEV float sigmoidf_(float x) { return 1.0f / (1.0f + expf(-x)); }

DEV float bf2f(unsigned u) { return __uint_as_float(u << 16); }
DEV unsigned f2bf(float f) {  // round-to-nearest-even
    unsigned u = __float_as_uint(f);
    return (u + 0x7fffu + ((u >> 16) & 1u)) >> 16;
}
DEV unsigned pack2(float a, float b) { return f2bf(a) | (f2bf(b) << 16); }

// async global->LDS: dst = wave-uniform base + lane*size, src per-lane
DEV void gl2lds16(const void* g, void* l) {
    __builtin_amdgcn_global_load_lds(
        (const __attribute__((address_space(1))) unsigned int*)g,
        (__attribute__((address_space(3))) unsigned int*)l, 16, 0, 0);
}
DEV void gl2lds4(const void* g, void* l) {
    __builtin_amdgcn_global_load_lds(
        (const __attribute__((address_space(1))) unsigned int*)g,
        (__attribute__((address_space(3))) unsigned int*)l, 4, 0, 0);
}

// 16-lane butterfly sum via DPP
template <int CTRL>
DEV float dppadd(float x) {
    int y = __builtin_amdgcn_mov_dpp(__float_as_int(x), CTRL, 0xF, 0xF, true);
    return x + __int_as_float(y);
}
DEV float reduce16f(float x) {
    x = dppadd<0xB1>(x);
    x = dppadd<0x4E>(x);
    x = dppadd<0x141>(x);
    x = dppadd<0x140>(x);
    return x;
}

DEV float4 bflo(uint4 U) {
    return make_float4(bf2f(U.x & 0xffff), bf2f(U.x >> 16),
                       bf2f(U.y & 0xffff), bf2f(U.y >> 16));
}
DEV float4 bfhi(uint4 U) {
    return make_float4(bf2f(U.z & 0xffff), bf2f(U.z >> 16),
                       bf2f(U.w & 0xffff), bf2f(U.w >> 16));
}

DEV short4v lo4(short8 v) { short4v r; r[0]=v[0]; r[1]=v[1]; r[2]=v[2]; r[3]=v[3]; return r; }
DEV short4v hi4(short8 v) { short4v r; r[0]=v[4]; r[1]=v[5]; r[2]=v[6]; r[3]=v[7]; return r; }

// D = A(16x16) @ B(16x16)^T + C. A/B frag: row = lane&15, k = (lane>>4)*4+j.
// C/D: col = lane&15, row = (lane>>4)*4 + reg.
DEV f32x4 mfma16(short4v a, short4v b, f32x4 c) {
#if __has_builtin(__builtin_amdgcn_mfma_f32_16x16x16bf16_1k)
    return __builtin_amdgcn_mfma_f32_16x16x16bf16_1k(a, b, c, 0, 0, 0);
#elif __has_builtin(__builtin_amdgcn_mfma_f32_16x16x16_bf16)
    return __builtin_amdgcn_mfma_f32_16x16x16_bf16(a, b, c, 0, 0, 0);
#else
    asm volatile("s_nop 1\n\t"
                 "v_mfma_f32_16x16x16_bf16 %0, %1, %2, %0\n\t"
                 "s_nop 7\n\t"
                 "s_nop 7"
                 : "+v"(c) : "v"(a), "v"(b));
    return c;
#endif
}

// ---------------------------------------------------------------------------
// bf16 MFMA GEMM (unchanged): C[M,N] = A[M,K] @ Bt[N,K]^T.
// ---------------------------------------------------------------------------
template <int OUTBF>
__global__ __launch_bounds__(256) void gemm_bf16(
    const unsigned short* __restrict__ A, const unsigned short* __restrict__ Bt,
    void* __restrict__ Cv, int Md, int Nd, int Kd)
{
    __shared__ unsigned short As[128 * 64];
    __shared__ unsigned short Bs[128 * 64];

    const int nbx = Nd >> 7;
    const int bx = blockIdx.x % nbx;
    const int by = blockIdx.x / nbx;
    const int m0 = by << 7, n0 = bx << 7;
    const int tid = threadIdx.x;
    const int lane = tid & 63, wid = tid >> 6;
    const int wr = wid >> 1, wc = wid & 1;

    const int srow  = tid >> 3;
    const int sslot = (tid & 7) ^ (srow & 7);
    const unsigned short* ag = A  + (size_t)(m0 + srow) * Kd + sslot * 8;
    const unsigned short* bg = Bt + (size_t)(n0 + srow) * Kd + sslot * 8;
    const size_t rstep32 = (size_t)32 * Kd;
    unsigned short* aw = As + wid * 512;
    unsigned short* bw = Bs + wid * 512;

    const int rrow  = lane & 15;
    const int khalf = lane >> 4;
    const int rswz  = rrow & 7;

    f32x4 zf = {0.f, 0.f, 0.f, 0.f};
    f32x4 acc[4][4];
#pragma unroll
    for (int m = 0; m < 4; m++)
#pragma unroll
        for (int n = 0; n < 4; n++) acc[m][n] = zf;

    for (int k0 = 0; k0 < Kd; k0 += 64) {
#pragma unroll
        for (int i = 0; i < 4; i++) {
            gl2lds16(ag + (size_t)i * rstep32 + k0, aw + i * 2048);
            gl2lds16(bg + (size_t)i * rstep32 + k0, bw + i * 2048);
        }
        __syncthreads();
#pragma unroll
        for (int kk = 0; kk < 2; kk++) {
            const int slot = (kk * 4 + khalf) ^ rswz;
            short8 a[4], b[4];
#pragma unroll
            for (int m = 0; m < 4; m++)
                a[m] = *(const short8*)&As[(wr * 64 + m * 16 + rrow) * 64 + slot * 8];
#pragma unroll
            for (int n = 0; n < 4; n++)
                b[n] = *(const short8*)&Bs[(wc * 64 + n * 16 + rrow) * 64 + slot * 8];
#pragma unroll
            for (int m = 0; m < 4; m++)
#pragma unroll
                for (int n = 0; n < 4; n++)
                    acc[m][n] = __builtin_amdgcn_mfma_f32_16x16x32_bf16(
                        a[m], b[n], acc[m][n], 0, 0, 0);
        }
        __syncthreads();
    }

#pragma unroll
    for (int m = 0; m < 4; m++) {
        const int rowb = m0 + wr * 64 + m * 16 + khalf * 4;
#pragma unroll
        for (int n = 0; n < 4; n++) {
            const int col = n0 + wc * 64 + n * 16 + rrow;
#pragma unroll
            for (int r = 0; r < 4; r++) {
                const float v = acc[m][n][r];
                if (OUTBF)
                    ((unsigned short*)Cv)[(size_t)(rowb + r) * Nd + col] =
                        (unsigned short)f2bf(v);
                else
                    ((float*)Cv)[(size_t)(rowb + r) * Nd + col] = v;
            }
        }
    }
}

// ---------------------------------------------------------------------------
// Weight transpose + bf16 convert (unchanged).
// ---------------------------------------------------------------------------
__global__ __launch_bounds__(256) void wtrans(
    const float* __restrict__ W, unsigned short* __restrict__ Wt, int Kd, int Nd)
{
    __shared__ float T[64][65];
    const int nbk = Kd >> 6;
    const int bk = blockIdx.x % nbk, bn = blockIdx.x / nbk;
    const int k0 = bk << 6, n0 = bn << 6;
    const int tid = threadIdx.x;
    {
        const int r = tid >> 2, cg = tid & 3;
#pragma unroll
        for (int i = 0; i < 4; i++) {
            float4 f = *(const float4*)&W[(size_t)(k0 + r) * Nd + n0 + cg * 16 + i * 4];
            T[r][cg * 16 + i * 4 + 0] = f.x;
            T[r][cg * 16 + i * 4 + 1] = f.y;
            T[r][cg * 16 + i * 4 + 2] = f.z;
            T[r][cg * 16 + i * 4 + 3] = f.w;
        }
    }
    __syncthreads();
    {
        const int n = tid >> 2, kg = tid & 3;
#pragma unroll
        for (int i = 0; i < 2; i++) {
            unsigned o[4];
#pragma unroll
            for (int j = 0; j < 4; j++) {
                const int kk = kg * 16 + i * 8 + 2 * j;
                o[j] = pack2(T[kk][n], T[kk + 1][n]);
            }
            *(uint4*)&Wt[(size_t)(n0 + n) * Kd + k0 + kg * 16 + i * 8] =
                make_uint4(o[0], o[1], o[2], o[3]);
        }
    }
}

// f32 -> bf16 bulk convert (unchanged)
__global__ __launch_bounds__(256) void f2bf_k(
    const float* __restrict__ x, unsigned short* __restrict__ y, int n8)
{
    const int i = blockIdx.x * blockDim.x + threadIdx.x;
    if (i < n8) {
        float4 a = *(const float4*)&x[(size_t)i * 8];
        float4 b = *(const float4*)&x[(size_t)i * 8 + 4];
        uint4 o = make_uint4(pack2(a.x, a.y), pack2(a.z, a.w),
                             pack2(b.x, b.y), pack2(b.z, b.w));
        *(uint4*)&y[(size_t)i * 8] = o;
    }
}

// ---------------------------------------------------------------------------
// Causal depthwise conv (K=4) + silu (+l2norm) (unchanged).
// ---------------------------------------------------------------------------
template <int MODE>
__global__ __launch_bounds__(256) void conv_silu(
    const unsigned short* __restrict__ pre, const float* __restrict__ cw,
    unsigned short* __restrict__ outp)
{
    const int m = blockIdx.x;
    const int t = m & (NT - 1);
    const int b = m >> 12;
    const int tid = threadIdx.x;
    const int hd = tid * 8;
    const int h  = hd >> 7;
    const int d0 = hd & 127;

    float xr[4][8];
#pragma unroll
    for (int i = 0; i < 4; i++) {
        const int tt = t - 3 + i;
        if (tt >= 0) {
            uint4 u = *(const uint4*)(pre + (size_t)(m - 3 + i) * ND + hd);
            float4 lo = bflo(u), hi = bfhi(u);
            xr[i][0] = lo.x; xr[i][1] = lo.y; xr[i][2] = lo.z; xr[i][3] = lo.w;
            xr[i][4] = hi.x; xr[i][5] = hi.y; xr[i][6] = hi.z; xr[i][7] = hi.w;
        } else {
#pragma unroll
            for (int j = 0; j < 8; j++) xr[i][j] = 0.f;
        }
    }
    float y[8];
    float ssum = 0.f;
#pragma unroll
    for (int j = 0; j < 8; j++) {
        float4 w = *(const float4*)&cw[(size_t)(hd + j) * 4];
        float v = xr[0][j] * w.x + xr[1][j] * w.y + xr[2][j] * w.z + xr[3][j] * w.w;
        v = v * sigmoidf_(v);
        y[j] = v;
        ssum += v * v;
    }
    float scale = 1.f;
    if (MODE >= 1) {
        ssum = reduce16f(ssum);
        scale = rsqrtf(ssum + 1e-6f);
        if (MODE == 2) scale *= 0.08838834764831845f;
    }
    uint4 pk;
    pk.x = pack2(y[0] * scale, y[1] * scale);
    pk.y = pack2(y[2] * scale, y[3] * scale);
    pk.z = pack2(y[4] * scale, y[5] * scale);
    pk.w = pack2(y[6] * scale, y[7] * scale);
    unsigned short* dst = outp + ((size_t)(b * NH + h) * NT + t) * 128 + d0;
    *(uint4*)dst = pk;
}

// ---------------------------------------------------------------------------
// gk[b,h,t,d] = -exp(A_log[h]) * softplus(g + dt_bias) stored FP16 (unchanged)
// ---------------------------------------------------------------------------
__global__ __launch_bounds__(256) void gk_k(
    const unsigned short* __restrict__ g, const float* __restrict__ A_log,
    const float* __restrict__ dtb, _Float16* __restrict__ gko)
{
    const int m = blockIdx.x;
    const int t = m & (NT - 1);
    const int b = m >> 12;
    const int tid = threadIdx.x;
    const int hd = tid * 8, h = hd >> 7, d0 = hd & 127;
    const float ea = expf(A_log[h]);
    uint4 u = *(const uint4*)(g + (size_t)m * ND + hd);
    float4 lo = bflo(u), hi = bfhi(u);
    float4 b0 = *(const float4*)&dtb[hd], b1 = *(const float4*)&dtb[hd + 4];
    float xin[8] = {lo.x + b0.x, lo.y + b0.y, lo.z + b0.z, lo.w + b0.w,
                    hi.x + b1.x, hi.y + b1.y, hi.z + b1.z, hi.w + b1.w};
    union { _Float16 h8[8]; uint4 u4; } up;
#pragma unroll
    for (int j = 0; j < 8; j++) {
        float x = xin[j];
        float sp = (x > 20.f) ? x : log1pf(expf(x));
        up.h8[j] = (_Float16)(-ea * sp);
    }
    _Float16* dst = gko + ((size_t)(b * NH + h) * NT + t) * 128 + d0;
    *(uint4*)dst = up.u4;
}

// ---------------------------------------------------------------------------
// beta[b,h,t] = sigmoid(hs @ b_w) (unchanged)
// ---------------------------------------------------------------------------
__global__ __launch_bounds__(256) void beta_k(
    const float* __restrict__ hs, const float* __restrict__ bw,
    float* __restrict__ bt)
{
    __shared__ float sh[ND];
    __shared__ float part[16][17];
    const int m = blockIdx.x, tid = threadIdx.x;
    ((float4*)sh)[tid * 2]     = ((const float4*)(hs + (size_t)m * ND))[tid * 2];
    ((float4*)sh)[tid * 2 + 1] = ((const float4*)(hs + (size_t)m * ND))[tid * 2 + 1];
    __syncthreads();
    const int h = tid & 15, seg = tid >> 4;
    float p = 0.f;
#pragma unroll 8
    for (int j = 0; j < 128; j++)
        p += sh[seg * 128 + j] * bw[(size_t)(seg * 128 + j) * 16 + h];
    part[seg][h] = p;
    __syncthreads();
    if (tid < 16) {
        float s = 0.f;
#pragma unroll
        for (int i = 0; i < 16; i++) s += part[i][tid];
        const int t = m & (NT - 1), b = m >> 12;
        bt[(size_t)(b * NH + tid) * NT + t] = sigmoidf_(s);
    }
}

// ---------------------------------------------------------------------------
// Phase 1 (parallel over 8192 chunks). Round 9: round-8 layouts + XOR bank
// swizzles (both-sides with scan4's LDS reads):
//   P'/q~: short off = row*128 + ((pair layout) ^ ((row&7)<<3))
//   khat : short off = ((krow-pair layout) ^ ((krow&7)<<3)) within 2048-blk
//   Bd   : float idx = ((si*16+sj) ^ ((si&7)<<2)) within 256-blk
//   vv (transposed), eCB: unchanged.
// ---------------------------------------------------------------------------
__global__ __launch_bounds__(256) void kda_prep(
    unsigned short* __restrict__ qn, unsigned short* __restrict__ kn,
    unsigned short* __restrict__ vv, unsigned short* __restrict__ gkh,
    const float* __restrict__ bt,
    float* __restrict__ BdB, float* __restrict__ eCB)
{
    __shared__ float cL[16][132];
    __shared__ float kL[16][132];
    __shared__ float qL[16][132];
    __shared__ float kapL[16][132];
    __shared__ float AbL[16][16];
    __shared__ float bL[16];
    __shared__ float sx[16][264];

    const int blk = blockIdx.x;
    const int bh  = blk >> 8;
    const int cc  = blk & 255;
    const int tid = threadIdx.x;
    const size_t ebase  = ((size_t)bh * NT + cc * 16) * 128;
    const size_t chbase = (size_t)bh * NCH + cc;

    if (tid < 16) bL[tid] = bt[(size_t)bh * NT + cc * 16 + tid];

    if (tid < 128) {
        const int d = tid;
        float c = 0.f;
#pragma unroll
        for (int i = 0; i < 16; i++) {
            float g = (float)(((const _Float16*)gkh)[ebase + i * 128 + d]);
            c += g;
            cL[i][d] = c;
            float kv = bf2f(kn[ebase + i * 128 + d]);
            float qv = bf2f(qn[ebase + i * 128 + d]);
            kL[i][d] = kv; qL[i][d] = qv;
            kapL[i][d] = kv * expf(c);
        }
        eCB[chbase * 128 + d] = expf(c);
    }
    __syncthreads();

    // khat^T write, pair-interleaved + XOR swizzle
    if (tid < 128) {
        const int d = tid;
        const int t = d >> 4, rr = d & 15;
        const int sw = (rr & 7) << 3;
        const float clast = cL[15][d];
        unsigned u[8];
#pragma unroll
        for (int e = 0; e < 8; e++) {
            float v0 = bL[2 * e]     * kL[2 * e][d]     * expf(clast - cL[2 * e][d]);
            float v1 = bL[2 * e + 1] * kL[2 * e + 1][d] * expf(clast - cL[2 * e + 1][d]);
            u[e] = pack2(v0, v1);
        }
        const unsigned bs = ((t >> 1) * 16 + rr) * 32 + (t & 1) * 4;
        unsigned short* base = gkh + chbase * 2048;
        *(uint2*)(base + ((bs +  0) ^ sw)) = make_uint2(u[0], u[1]);
        *(uint2*)(base + ((bs +  8) ^ sw)) = make_uint2(u[2], u[3]);
        *(uint2*)(base + ((bs + 16) ^ sw)) = make_uint2(u[4], u[5]);
        *(uint2*)(base + ((bs + 24) ^ sw)) = make_uint2(u[6], u[7]);
    }

    const int si = tid >> 4, sj = tid & 15;
    float aAcc = 0.f, bAcc = 0.f;
    if (si >= sj) {
        for (int d4 = 0; d4 < 128; d4 += 4) {
            float4 ci = *(const float4*)&cL[si][d4];
            float4 cj = *(const float4*)&cL[sj][d4];
            float4 ki = *(const float4*)&kL[si][d4];
            float4 kj = *(const float4*)&kL[sj][d4];
            float4 qi = *(const float4*)&qL[si][d4];
            float w;
            w = expf(ci.x - cj.x); aAcc += ki.x * kj.x * w; bAcc += qi.x * kj.x * w;
            w = expf(ci.y - cj.y); aAcc += ki.y * kj.y * w; bAcc += qi.y * kj.y * w;
            w = expf(ci.z - cj.z); aAcc += ki.z * kj.z * w; bAcc += qi.z * kj.z * w;
            w = expf(ci.w - cj.w); aAcc += ki.w * kj.w * w; bAcc += qi.w * kj.w * w;
        }
    }
    if (si > sj) AbL[si][sj] = aAcc * bL[sj];
    BdB[chbase * 256 + ((si * 16 + sj) ^ ((si & 7) << 2))] = bAcc * bL[sj];
    __syncthreads();

    // solve M x = r, M = I + tril(Ab): cols 0..127 kappa, 128..255 v
    {
        const int col = tid;
        float x[16];
#pragma unroll
        for (int i = 0; i < 16; i++)
            x[i] = (col < 128) ? kapL[i][col]
                               : bf2f(vv[ebase + (size_t)i * 128 + (col - 128)]);
#pragma unroll
        for (int i = 1; i < 16; i++) {
            float s = x[i];
#pragma unroll
            for (int l = 0; l < 15; l++)
                if (l < i) s -= AbL[i][l] * x[l];
            x[i] = s;
        }
#pragma unroll
        for (int i = 0; i < 16; i++) sx[i][col] = x[i];
    }
    __syncthreads();

    // P' / q~ writes, pair-interleaved + XOR swizzle
    {
        const int row = tid >> 4, q16 = tid & 15;
        const int d0 = q16 * 8;
        const int t  = q16 >> 1;
        const int pos0 = (t >> 1) * 32 + (t & 1) * 4 + (q16 & 1) * 16;
        const int sw = (row & 7) << 3;
        const int oA = pos0 ^ sw;
        const int oB = (pos0 + 8) ^ sw;
        unsigned pu[4], qu[4];
#pragma unroll
        for (int e = 0; e < 4; e++) {
            pu[e] = pack2(-sx[row][d0 + 2 * e], -sx[row][d0 + 2 * e + 1]);
            qu[e] = pack2(qL[row][d0 + 2 * e]     * expf(cL[row][d0 + 2 * e]),
                          qL[row][d0 + 2 * e + 1] * expf(cL[row][d0 + 2 * e + 1]));
        }
        unsigned short* kb = kn + ebase + (size_t)row * 128;
        unsigned short* qb = qn + ebase + (size_t)row * 128;
        *(uint2*)(kb + oA) = make_uint2(pu[0], pu[1]);
        *(uint2*)(kb + oB) = make_uint2(pu[2], pu[3]);
        *(uint2*)(qb + oA) = make_uint2(qu[0], qu[1]);
        *(uint2*)(qb + oB) = make_uint2(qu[2], qu[3]);
    }
    // V' transposed write (unchanged)
    if (tid < 128) {
        const int c = tid;
        unsigned u2[8];
#pragma unroll
        for (int e = 0; e < 8; e++)
            u2[e] = pack2(sx[2 * e][128 + c], sx[2 * e + 1][128 + c]);
        unsigned short* vb = vv + ebase + (size_t)c * 16;
        *(uint4*)(vb)     = make_uint4(u2[0], u2[1], u2[2], u2[3]);
        *(uint4*)(vb + 8) = make_uint4(u2[4], u2[5], u2[6], u2[7]);
    }
}

// ---------------------------------------------------------------------------
// Phase 2 scan4: 256 blocks (bh,vg) x 1 wave. Async chunk pipeline:
// issue chunk cc+1 into LDS buf^1 (17 global_load_lds), s_waitcnt vmcnt(17),
// compute chunk cc from LDS buf (XOR-swizzled ds_read_b128). No barriers.
// ---------------------------------------------------------------------------
__global__ __launch_bounds__(64) void kda_scan4(
    const unsigned short* __restrict__ qn, const unsigned short* __restrict__ kn,
    const unsigned short* __restrict__ vv, const unsigned short* __restrict__ khat,
    const float* __restrict__ BdB, const float* __restrict__ eCB,
    float* __restrict__ osc)
{
    __shared__ unsigned short Pl[2][2048];
    __shared__ unsigned short Ql[2][2048];
    __shared__ unsigned short KHl[2][2048];
    __shared__ unsigned short Vl[2][256];
    __shared__ float eCl[2][128];
    __shared__ float Bdl[2][256];

    const int bh = blockIdx.x & 31;   // same bh -> same XCD (32 % 8 == 0)
    const int vg = blockIdx.x >> 5;
    const int lane = threadIdx.x;
    const int r16 = lane & 15, h4 = lane >> 4;
    const int bb = bh >> 4, hh = bh & 15;
    const int sw = (r16 & 7) << 3;    // short-offset XOR (bytes: <<4)

    f32x4 Sm[8];
    short4v Shi[8];
    const short4v z4 = {0, 0, 0, 0};
#pragma unroll
    for (int t = 0; t < 8; t++) { Sm[t] = (f32x4){0.f, 0.f, 0.f, 0.f}; Shi[t] = z4; }

    auto issue = [&](int cc, int buf) {
        const size_t ebase = ((size_t)bh * NT + cc * 16) * 128;
        const size_t chb = (size_t)bh * NCH + cc;
#pragma unroll
        for (int i = 0; i < 4; i++) {
            gl2lds16(kn + ebase + i * 512 + lane * 8, &Pl[buf][i * 512]);
            gl2lds16(qn + ebase + i * 512 + lane * 8, &Ql[buf][i * 512]);
            gl2lds16(khat + chb * 2048 + i * 512 + lane * 8, &KHl[buf][i * 512]);
        }
#pragma unroll
        for (int j = 0; j < 2; j++) {
            gl2lds4((const char*)(vv + ebase + (size_t)vg * 256) + j * 256 + lane * 4,
                    &Vl[buf][j * 128]);
            gl2lds4((const char*)(eCB + chb * 128) + j * 256 + lane * 4,
                    &eCl[buf][j * 64]);
        }
        gl2lds16((const char*)(BdB + chb * 256) + lane * 16, &Bdl[buf][0]);
    };

    issue(0, 0);
    for (int cc = 0; cc < NCH; ++cc) {
        const int cur = cc & 1;
        if (cc + 1 < NCH) {
            issue(cc + 1, cur ^ 1);
            asm volatile("s_waitcnt vmcnt(17)" ::: "memory");
        } else {
            asm volatile("s_waitcnt vmcnt(0)" ::: "memory");
        }
        __builtin_amdgcn_sched_barrier(0);

        const unsigned short* Pb  = &Pl[cur][0];
        const unsigned short* Qb  = &Ql[cur][0];
        const unsigned short* KHb = &KHl[cur][0];

        short8 Pp[4], Qp[4], KHp[4];
#pragma unroll
        for (int m = 0; m < 4; m++) {
            const int po = r16 * 128 + ((m * 32 + h4 * 8) ^ sw);
            Pp[m]  = *(const short8*)&Pb[po];
            Qp[m]  = *(const short8*)&Qb[po];
            KHp[m] = *(const short8*)&KHb[((m * 16 + r16) * 32 + h4 * 8) ^ sw];
        }
        short4v vvt = *(const short4v*)&Vl[cur][r16 * 16 + h4 * 4];
        float4 eCt[8];
#pragma unroll
        for (int t = 0; t < 8; t++)
            eCt[t] = *(const float4*)&eCl[cur][t * 16 + h4 * 4];
        float4 bd4 = *(const float4*)&Bdl[cur][(r16 * 16 + h4 * 4) ^ ((r16 & 7) << 2)];
        short4v bdf;
        bdf[0] = (short)f2bf(bd4.x); bdf[1] = (short)f2bf(bd4.y);
        bdf[2] = (short)f2bf(bd4.z); bdf[3] = (short)f2bf(bd4.w);

        // err / o chains (4 independent chains of 4 MFMAs)
        f32x4 e0, e1 = {0.f, 0.f, 0.f, 0.f};
        f32x4 o0 = {0.f, 0.f, 0.f, 0.f}, o1 = {0.f, 0.f, 0.f, 0.f};
        e0[0] = bf2f((unsigned short)vvt[0]); e0[1] = bf2f((unsigned short)vvt[1]);
        e0[2] = bf2f((unsigned short)vvt[2]); e0[3] = bf2f((unsigned short)vvt[3]);
#pragma unroll
        for (int m = 0; m < 4; m++) {
            e0 = mfma16(lo4(Pp[m]), Shi[2 * m],     e0);
            e1 = mfma16(hi4(Pp[m]), Shi[2 * m + 1], e1);
            o0 = mfma16(lo4(Qp[m]), Shi[2 * m],     o0);
            o1 = mfma16(hi4(Qp[m]), Shi[2 * m + 1], o1);
        }
        f32x4 accE, accO;
        accE[0] = e0[0] + e1[0]; accE[1] = e0[1] + e1[1];
        accE[2] = e0[2] + e1[2]; accE[3] = e0[3] + e1[3];
        accO[0] = o0[0] + o1[0]; accO[1] = o0[1] + o1[1];
        accO[2] = o0[2] + o1[2]; accO[3] = o0[3] + o1[3];

        short4v ef;
        ef[0] = (short)f2bf(accE[0]); ef[1] = (short)f2bf(accE[1]);
        ef[2] = (short)f2bf(accE[2]); ef[3] = (short)f2bf(accE[3]);
        accO = mfma16(bdf, ef, accO);

        // state update (8 independent MFMAs)
#pragma unroll
        for (int t = 0; t < 8; t++) {
            const short4v khf = (t & 1) ? hi4(KHp[t >> 1]) : lo4(KHp[t >> 1]);
            f32x4 ns;
            ns[0] = eCt[t].x * Sm[t][0];
            ns[1] = eCt[t].y * Sm[t][1];
            ns[2] = eCt[t].z * Sm[t][2];
            ns[3] = eCt[t].w * Sm[t][3];
            ns = mfma16(khf, ef, ns);
            Sm[t] = ns;
            short4v nh;
            nh[0] = (short)f2bf(ns[0]); nh[1] = (short)f2bf(ns[1]);
            nh[2] = (short)f2bf(ns[2]); nh[3] = (short)f2bf(ns[3]);
            Shi[t] = nh;
        }

        // o write: rows i = h4*4+r, col hh*128 + vg*16 + r16
        const size_t obase = ((size_t)bb * NT + cc * 16) * ND + hh * 128 + vg * 16 + r16;
#pragma unroll
        for (int r = 0; r < 4; r++)
            osc[obase + (size_t)(h4 * 4 + r) * ND] = accO[r];
    }
}

// ---------------------------------------------------------------------------
// Gated RMSNorm epilogue (unchanged).
// ---------------------------------------------------------------------------
__global__ __launch_bounds__(256) void gate_k(
    const float* __restrict__ osc, const unsigned short* __restrict__ gateb,
    const float* __restrict__ gb2, const float* __restrict__ onw,
    unsigned short* __restrict__ ogb)
{
    const int m = blockIdx.x, tid = threadIdx.x;
    const int hd = tid * 8, d0 = hd & 127;
    const float* op = osc + (size_t)m * ND + hd;
    float4 o0 = *(const float4*)op, o1 = *(const float4*)(op + 4);
    float ssum = o0.x * o0.x + o0.y * o0.y + o0.z * o0.z + o0.w * o0.w +
                 o1.x * o1.x + o1.y * o1.y + o1.z * o1.z + o1.w * o1.w;
    ssum = reduce16f(ssum);
    const float r = rsqrtf(ssum * (1.0f / 128.0f) + 1e-5f);
    uint4 gu = *(const uint4*)(gateb + (size_t)m * ND + hd);
    float4 gl = bflo(gu), gh = bfhi(gu);
    float4 b0 = *(const float4*)&gb2[hd], b1 = *(const float4*)&gb2[hd + 4];
    float4 w0 = *(const float4*)&onw[d0], w1 = *(const float4*)&onw[d0 + 4];
    float res[8];
    res[0] = o0.x * r * w0.x * sigmoidf_(gl.x + b0.x);
    res[1] = o0.y * r * w0.y * sigmoidf_(gl.y + b0.y);
    res[2] = o0.z * r * w0.z * sigmoidf_(gl.z + b0.z);
    res[3] = o0.w * r * w0.w * sigmoidf_(gl.w + b0.w);
    res[4] = o1.x * r * w1.x * sigmoidf_(gh.x + b1.x);
    res[5] = o1.y * r * w1.y * sigmoidf_(gh.y + b1.y);
    res[6] = o1.z * r * w1.z * sigmoidf_(gh.z + b1.z);
    res[7] = o1.w * r * w1.w * sigmoidf_(gh.w + b1.w);
    uint4 pk;
    pk.x = pack2(res[0], res[1]); pk.y = pack2(res[2], res[3]);
    pk.z = pack2(res[4], res[5]); pk.w = pack2(res[6], res[7]);
    *(uint4*)(ogb + (size_t)m * ND + hd) = pk;
}

__global__ void diag_fill(float* out, float val, int n) {
    for (int i = blockIdx.x * blockDim.x + threadIdx.x; i < n; i += gridDim.x * blockDim.x)
        out[i] = val;
}

// ---------------------------------------------------------------------------
extern "C" void kernel_launch(void* const* d_in, const int* in_sizes, int n_in,
                              void* d_out, int out_size, void* d_ws, size_t ws_size,
                              hipStream_t stream)
{
    const float* hs    = (const float*)d_in[0];
    const float* q_w   = (const float*)d_in[1];
    const float* k_w   = (const float*)d_in[2];
    const float* v_w   = (const float*)d_in[3];
    const float* qcw   = (const float*)d_in[4];
    const float* kcw   = (const float*)d_in[5];
    const float* vcw   = (const float*)d_in[6];
    const float* f_w1  = (const float*)d_in[7];
    const float* f_w2  = (const float*)d_in[8];
    const float* b_w   = (const float*)d_in[9];
    const float* A_log = (const float*)d_in[10];
    const float* dt_b  = (const float*)d_in[11];
    const float* g_w1  = (const float*)d_in[12];
    const float* g_w2  = (const float*)d_in[13];
    const float* g_b2  = (const float*)d_in[14];
    const float* onw   = (const float*)d_in[15];
    const float* o_w   = (const float*)d_in[16];
    float* out = (float*)d_out;

    // ---- workspace layout (bytes), peak ~187 MB ----------------------------
    const size_t SEQ = (size_t)BHN * NT;           // 131072
    const size_t BF  = SEQ * 128 * 2;              // bf16 stream: 32 MiB
    char* wsb = (char*)d_ws;
    size_t off = 0;
    unsigned short* qn   = (unsigned short*)(wsb + off); off += BF;
    unsigned short* kn   = (unsigned short*)(wsb + off); off += BF;
    unsigned short* vv   = (unsigned short*)(wsb + off); off += BF;  // ogb post-scan
    unsigned short* dc   = (unsigned short*)(wsb + off); off += BF;  // gk fp16 -> khat
    unsigned short* P1   = (unsigned short*)(wsb + off); off += (size_t)MROWS * ND * 2;
    unsigned short* WT   = (unsigned short*)(wsb + off); off += (size_t)ND * ND * 2;
    unsigned short* fw1t = (unsigned short*)(wsb + off); off += (size_t)DK * ND * 2;
    unsigned short* fw2t = (unsigned short*)(wsb + off); off += (size_t)ND * DK * 2;
    unsigned short* gw1t = (unsigned short*)(wsb + off); off += (size_t)DK * ND * 2;
    unsigned short* gw2t = (unsigned short*)(wsb + off); off += (size_t)ND * DK * 2;
    unsigned short* f1b  = (unsigned short*)(wsb + off); off += (size_t)MROWS * DK * 2;
    unsigned short* g1b  = (unsigned short*)(wsb + off); off += (size_t)MROWS * DK * 2;
    float* bt  = (float*)(wsb + off); off += SEQ * 4;
    float* BdB = (float*)(wsb + off); off += (size_t)BHN * NCH * 256 * 4;  // 8 MiB
    float* eCB = (float*)(wsb + off); off += (size_t)BHN * NCH * 128 * 4;  // 4 MiB
    unsigned short* ogb = vv;
    unsigned short* hsb = (unsigned short*)d_out;

    if (ws_size < off) {
        diag_fill<<<512, 256, 0, stream>>>(out, 1.0e6f + (float)(ws_size >> 20), out_size);
        return;
    }

    dim3 blk(256);
    auto g2 = [](int Md, int Nd) { return dim3((unsigned)((Md >> 7) * (Nd >> 7))); };
    auto gt = [](int Kd, int Nd) { return dim3((unsigned)((Kd >> 6) * (Nd >> 6))); };

    // 0. hs -> bf16 (staged in d_out; consumed before scan4 overwrites)
    f2bf_k<<<(MROWS * ND / 8 + 255) / 256, blk, 0, stream>>>(hs, hsb, MROWS * ND / 8);

    // 1. q/k/v projections + conv/silu(/l2norm)
    wtrans<<<gt(ND, ND), blk, 0, stream>>>(q_w, WT, ND, ND);
    gemm_bf16<1><<<g2(MROWS, ND), blk, 0, stream>>>(hsb, WT, P1, MROWS, ND, ND);
    conv_silu<2><<<MROWS, blk, 0, stream>>>(P1, qcw, qn);
    wtrans<<<gt(ND, ND), blk, 0, stream>>>(k_w, WT, ND, ND);
    gemm_bf16<1><<<g2(MROWS, ND), blk, 0, stream>>>(hsb, WT, P1, MROWS, ND, ND);
    conv_silu<1><<<MROWS, blk, 0, stream>>>(P1, kcw, kn);
    wtrans<<<gt(ND, ND), blk, 0, stream>>>(v_w, WT, ND, ND);
    gemm_bf16<1><<<g2(MROWS, ND), blk, 0, stream>>>(hsb, WT, P1, MROWS, ND, ND);
    conv_silu<0><<<MROWS, blk, 0, stream>>>(P1, vcw, vv);

    // 2. decay path -> gk fp16
    wtrans<<<gt(ND, DK), blk, 0, stream>>>(f_w1, fw1t, ND, DK);
    gemm_bf16<1><<<g2(MROWS, DK), blk, 0, stream>>>(hsb, fw1t, f1b, MROWS, DK, ND);
    wtrans<<<gt(DK, ND), blk, 0, stream>>>(f_w2, fw2t, DK, ND);
    gemm_bf16<1><<<g2(MROWS, ND), blk, 0, stream>>>(f1b, fw2t, P1, MROWS, ND, DK);
    gk_k<<<MROWS, blk, 0, stream>>>(P1, A_log, dt_b, (_Float16*)dc);

    // 3. output gate preact -> P1 (survives scan, consumed by gate_k)
    wtrans<<<gt(ND, DK), blk, 0, stream>>>(g_w1, gw1t, ND, DK);
    gemm_bf16<1><<<g2(MROWS, DK), blk, 0, stream>>>(hsb, gw1t, g1b, MROWS, DK, ND);
    wtrans<<<gt(DK, ND), blk, 0, stream>>>(g_w2, gw2t, DK, ND);
    gemm_bf16<1><<<g2(MROWS, ND), blk, 0, stream>>>(g1b, gw2t, P1, MROWS, ND, DK);

    // 4. beta
    beta_k<<<MROWS, blk, 0, stream>>>(hs, b_w, bt);

    // 5. chunked delta rule: prep (parallel) + scan4 (serial chunks, async LDS)
    kda_prep<<<BHN * NCH, blk, 0, stream>>>(qn, kn, vv, dc, bt, BdB, eCB);
    kda_scan4<<<BHN * 8, 64, 0, stream>>>(qn, kn, vv, dc, BdB, eCB, out);

    // 6. gated RMSNorm -> ogb bf16 (aliases vv)
    gate_k<<<MROWS, blk, 0, stream>>>(out, P1, g_b2, onw, ogb);

    // 7. final projection
    wtrans<<<gt(ND, ND), blk, 0, stream>>>(o_w, WT, ND, ND);
    gemm_bf16<0><<<g2(MROWS, ND), blk, 0, stream>>>(ogb, WT, out, MROWS, ND, ND);
}

// Round 11
// 1215.032 us; speedup vs baseline: 1.0022x; 1.0022x over previous
//
#include <hip/hip_runtime.h>
#include <math.h>

// ---------------------------------------------------------------------------
// KimiDeltaAttention forward, MI355X. Round 9: scan4 = 256 blocks x 1 wave
// (scan2 placement) + async global_load_lds double-buffered chunk pipeline
// with counted s_waitcnt vmcnt(17) (T3/T4), XOR bank-swizzle baked into
// prep's P'/q~/khat/Bd layouts (both-sides, rule #21). GEMMs unchanged.
// Shapes fixed: B=2, T=4096, D=2048, H=16, Dk=Dv=128.
// ---------------------------------------------------------------------------

constexpr int NB = 2, NT = 4096, ND = 2048, NH = 16, DK = 128, DV = 128;
constexpr int MROWS = NB * NT;   // 8192
constexpr int BHN   = NB * NH;   // 32
constexpr int CCH   = 16;        // chunk length
constexpr int NCH   = NT / CCH;  // 256 chunks per sequence

#define DEV static __device__ __forceinline__

typedef __attribute__((ext_vector_type(8))) short short8;   // bf16x8 MFMA frag
typedef __attribute__((ext_vector_type(4))) short short4v;  // bf16x4 MFMA frag
typedef __attribute__((ext_vector_type(4))) float f32x4;    // MFMA acc frag

DEV float sigmoidf_(float x) { return 1.0f / (1.0f + expf(-x)); }

DEV float bf2f(unsigned u) { return __uint_as_float(u << 16); }
DEV unsigned f2bf(float f) {  // round-to-nearest-even
    unsigned u = __float_as_uint(f);
    return (u + 0x7fffu + ((u >> 16) & 1u)) >> 16;
}
DEV unsigned pack2(float a, float b) { return f2bf(a) | (f2bf(b) << 16); }

// async global->LDS: dst = wave-uniform base + lane*size, src per-lane
DEV void gl2lds16(const void* g, void* l) {
    __builtin_amdgcn_global_load_lds(
        (const __attribute__((address_space(1))) unsigned int*)g,
        (__attribute__((address_space(3))) unsigned int*)l, 16, 0, 0);
}
DEV void gl2lds4(const void* g, void* l) {
    __builtin_amdgcn_global_load_lds(
        (const __attribute__((address_space(1))) unsigned int*)g,
        (__attribute__((address_space(3))) unsigned int*)l, 4, 0, 0);
}

// 16-lane butterfly sum via DPP
template <int CTRL>
DEV float dppadd(float x) {
    int y = __builtin_amdgcn_mov_dpp(__float_as_int(x), CTRL, 0xF, 0xF, true);
    return x + __int_as_float(y);
}
DEV float reduce16f(float x) {
    x = dppadd<0xB1>(x);
    x = dppadd<0x4E>(x);
    x = dppadd<0x141>(x);
    x = dppadd<0x140>(x);
    return x;
}

DEV float4 bflo(uint4 U) {
    return make_float4(bf2f(U.x & 0xffff), bf2f(U.x >> 16),
                       bf2f(U.y & 0xffff), bf2f(U.y >> 16));
}
DEV float4 bfhi(uint4 U) {
    return make_float4(bf2f(U.z & 0xffff), bf2f(U.z >> 16),
                       bf2f(U.w & 0xffff), bf2f(U.w >> 16));
}

DEV short4v lo4(short8 v) { short4v r; r[0]=v[0]; r[1]=v[1]; r[2]=v[2]; r[3]=v[3]; return r; }
DEV short4v hi4(short8 v) { short4v r; r[0]=v[4]; r[1]=v[5]; r[2]=v[6]; r[3]=v[7]; return r; }

// D = A(16x16) @ B(16x16)^T + C. A/B frag: row = lane&15, k = (lane>>4)*4+j.
// C/D: col = lane&15, row = (lane>>4)*4 + reg.
DEV f32x4 mfma16(short4v a, short4v b, f32x4 c) {
#if __has_builtin(__builtin_amdgcn_mfma_f32_16x16x16bf16_1k)
    return __builtin_amdgcn_mfma_f32_16x16x16bf16_1k(a, b, c, 0, 0, 0);
#elif __has_builtin(__builtin_amdgcn_mfma_f32_16x16x16_bf16)
    return __builtin_amdgcn_mfma_f32_16x16x16_bf16(a, b, c, 0, 0, 0);
#else
    asm volatile("s_nop 1\n\t"
                 "v_mfma_f32_16x16x16_bf16 %0, %1, %2, %0\n\t"
                 "s_nop 7\n\t"
                 "s_nop 7"
                 : "+v"(c) : "v"(a), "v"(b));
    return c;
#endif
}

// ---------------------------------------------------------------------------
// bf16 MFMA GEMM (unchanged): C[M,N] = A[M,K] @ Bt[N,K]^T.
// ---------------------------------------------------------------------------
template <int OUTBF>
__global__ __launch_bounds__(256) void gemm_bf16(
    const unsigned short* __restrict__ A, const unsigned short* __restrict__ Bt,
    void* __restrict__ Cv, int Md, int Nd, int Kd)
{
    __shared__ unsigned short As[128 * 64];
    __shared__ unsigned short Bs[128 * 64];

    const int nbx = Nd >> 7;
    const int bx = blockIdx.x % nbx;
    const int by = blockIdx.x / nbx;
    const int m0 = by << 7, n0 = bx << 7;
    const int tid = threadIdx.x;
    const int lane = tid & 63, wid = tid >> 6;
    const int wr = wid >> 1, wc = wid & 1;

    const int srow  = tid >> 3;
    const int sslot = (tid & 7) ^ (srow & 7);
    const unsigned short* ag = A  + (size_t)(m0 + srow) * Kd + sslot * 8;
    const unsigned short* bg = Bt + (size_t)(n0 + srow) * Kd + sslot * 8;
    const size_t rstep32 = (size_t)32 * Kd;
    unsigned short* aw = As + wid * 512;
    unsigned short* bw = Bs + wid * 512;

    const int rrow  = lane & 15;
    const int khalf = lane >> 4;
    const int rswz  = rrow & 7;

    f32x4 zf = {0.f, 0.f, 0.f, 0.f};
    f32x4 acc[4][4];
#pragma unroll
    for (int m = 0; m < 4; m++)
#pragma unroll
        for (int n = 0; n < 4; n++) acc[m][n] = zf;

    for (int k0 = 0; k0 < Kd; k0 += 64) {
#pragma unroll
        for (int i = 0; i < 4; i++) {
            gl2lds16(ag + (size_t)i * rstep32 + k0, aw + i * 2048);
            gl2lds16(bg + (size_t)i * rstep32 + k0, bw + i * 2048);
        }
        __syncthreads();
#pragma unroll
        for (int kk = 0; kk < 2; kk++) {
            const int slot = (kk * 4 + khalf) ^ rswz;
            short8 a[4], b[4];
#pragma unroll
            for (int m = 0; m < 4; m++)
                a[m] = *(const short8*)&As[(wr * 64 + m * 16 + rrow) * 64 + slot * 8];
#pragma unroll
            for (int n = 0; n < 4; n++)
                b[n] = *(const short8*)&Bs[(wc * 64 + n * 16 + rrow) * 64 + slot * 8];
#pragma unroll
            for (int m = 0; m < 4; m++)
#pragma unroll
                for (int n = 0; n < 4; n++)
                    acc[m][n] = __builtin_amdgcn_mfma_f32_16x16x32_bf16(
                        a[m], b[n], acc[m][n], 0, 0, 0);
        }
        __syncthreads();
    }

#pragma unroll
    for (int m = 0; m < 4; m++) {
        const int rowb = m0 + wr * 64 + m * 16 + khalf * 4;
#pragma unroll
        for (int n = 0; n < 4; n++) {
            const int col = n0 + wc * 64 + n * 16 + rrow;
#pragma unroll
            for (int r = 0; r < 4; r++) {
                const float v = acc[m][n][r];
                if (OUTBF)
                    ((unsigned short*)Cv)[(size_t)(rowb + r) * Nd + col] =
                        (unsigned short)f2bf(v);
                else
                    ((float*)Cv)[(size_t)(rowb + r) * Nd + col] = v;
            }
        }
    }
}

// ---------------------------------------------------------------------------
// Weight transpose + bf16 convert (unchanged).
// ---------------------------------------------------------------------------
__global__ __launch_bounds__(256) void wtrans(
    const float* __restrict__ W, unsigned short* __restrict__ Wt, int Kd, int Nd)
{
    __shared__ float T[64][65];
    const int nbk = Kd >> 6;
    const int bk = blockIdx.x % nbk, bn = blockIdx.x / nbk;
    const int k0 = bk << 6, n0 = bn << 6;
    const int tid = threadIdx.x;
    {
        const int r = tid >> 2, cg = tid & 3;
#pragma unroll
        for (int i = 0; i < 4; i++) {
            float4 f = *(const float4*)&W[(size_t)(k0 + r) * Nd + n0 + cg * 16 + i * 4];
            T[r][cg * 16 + i * 4 + 0] = f.x;
            T[r][cg * 16 + i * 4 + 1] = f.y;
            T[r][cg * 16 + i * 4 + 2] = f.z;
            T[r][cg * 16 + i * 4 + 3] = f.w;
        }
    }
    __syncthreads();
    {
        const int n = tid >> 2, kg = tid & 3;
#pragma unroll
        for (int i = 0; i < 2; i++) {
            unsigned o[4];
#pragma unroll
            for (int j = 0; j < 4; j++) {
                const int kk = kg * 16 + i * 8 + 2 * j;
                o[j] = pack2(T[kk][n], T[kk + 1][n]);
            }
            *(uint4*)&Wt[(size_t)(n0 + n) * Kd + k0 + kg * 16 + i * 8] =
                make_uint4(o[0], o[1], o[2], o[3]);
        }
    }
}

// f32 -> bf16 bulk convert (unchanged)
__global__ __launch_bounds__(256) void f2bf_k(
    const float* __restrict__ x, unsigned short* __restrict__ y, int n8)
{
    const int i = blockIdx.x * blockDim.x + threadIdx.x;
    if (i < n8) {
        float4 a = *(const float4*)&x[(size_t)i * 8];
        float4 b = *(const float4*)&x[(size_t)i * 8 + 4];
        uint4 o = make_uint4(pack2(a.x, a.y), pack2(a.z, a.w),
                             pack2(b.x, b.y), pack2(b.z, b.w));
        *(uint4*)&y[(size_t)i * 8] = o;
    }
}

// ---------------------------------------------------------------------------
// Causal depthwise conv (K=4) + silu (+l2norm) (unchanged).
// ---------------------------------------------------------------------------
template <int MODE>
__global__ __launch_bounds__(256) void conv_silu(
    const unsigned short* __restrict__ pre, const float* __restrict__ cw,
    unsigned short* __restrict__ outp)
{
    const int m = blockIdx.x;
    const int t = m & (NT - 1);
    const int b = m >> 12;
    const int tid = threadIdx.x;
    const int hd = tid * 8;
    const int h  = hd >> 7;
    const int d0 = hd & 127;

    float xr[4][8];
#pragma unroll
    for (int i = 0; i < 4; i++) {
        const int tt = t - 3 + i;
        if (tt >= 0) {
            uint4 u = *(const uint4*)(pre + (size_t)(m - 3 + i) * ND + hd);
            float4 lo = bflo(u), hi = bfhi(u);
            xr[i][0] = lo.x; xr[i][1] = lo.y; xr[i][2] = lo.z; xr[i][3] = lo.w;
            xr[i][4] = hi.x; xr[i][5] = hi.y; xr[i][6] = hi.z; xr[i][7] = hi.w;
        } else {
#pragma unroll
            for (int j = 0; j < 8; j++) xr[i][j] = 0.f;
        }
    }
    float y[8];
    float ssum = 0.f;
#pragma unroll
    for (int j = 0; j < 8; j++) {
        float4 w = *(const float4*)&cw[(size_t)(hd + j) * 4];
        float v = xr[0][j] * w.x + xr[1][j] * w.y + xr[2][j] * w.z + xr[3][j] * w.w;
        v = v * sigmoidf_(v);
        y[j] = v;
        ssum += v * v;
    }
    float scale = 1.f;
    if (MODE >= 1) {
        ssum = reduce16f(ssum);
        scale = rsqrtf(ssum + 1e-6f);
        if (MODE == 2) scale *= 0.08838834764831845f;
    }
    uint4 pk;
    pk.x = pack2(y[0] * scale, y[1] * scale);
    pk.y = pack2(y[2] * scale, y[3] * scale);
    pk.z = pack2(y[4] * scale, y[5] * scale);
    pk.w = pack2(y[6] * scale, y[7] * scale);
    unsigned short* dst = outp + ((size_t)(b * NH + h) * NT + t) * 128 + d0;
    *(uint4*)dst = pk;
}

// ---------------------------------------------------------------------------
// gk[b,h,t,d] = -exp(A_log[h]) * softplus(g + dt_bias) stored FP16 (unchanged)
// ---------------------------------------------------------------------------
__global__ __launch_bounds__(256) void gk_k(
    const unsigned short* __restrict__ g, const float* __restrict__ A_log,
    const float* __restrict__ dtb, _Float16* __restrict__ gko)
{
    const int m = blockIdx.x;
    const int t = m & (NT - 1);
    const int b = m >> 12;
    const int tid = threadIdx.x;
    const int hd = tid * 8, h = hd >> 7, d0 = hd & 127;
    const float ea = expf(A_log[h]);
    uint4 u = *(const uint4*)(g + (size_t)m * ND + hd);
    float4 lo = bflo(u), hi = bfhi(u);
    float4 b0 = *(const float4*)&dtb[hd], b1 = *(const float4*)&dtb[hd + 4];
    float xin[8] = {lo.x + b0.x, lo.y + b0.y, lo.z + b0.z, lo.w + b0.w,
                    hi.x + b1.x, hi.y + b1.y, hi.z + b1.z, hi.w + b1.w};
    union { _Float16 h8[8]; uint4 u4; } up;
#pragma unroll
    for (int j = 0; j < 8; j++) {
        float x = xin[j];
        float sp = (x > 20.f) ? x : log1pf(expf(x));
        up.h8[j] = (_Float16)(-ea * sp);
    }
    _Float16* dst = gko + ((size_t)(b * NH + h) * NT + t) * 128 + d0;
    *(uint4*)dst = up.u4;
}

// ---------------------------------------------------------------------------
// beta[b,h,t] = sigmoid(hs @ b_w) (unchanged)
// ---------------------------------------------------------------------------
__global__ __launch_bounds__(256) void beta_k(
    const float* __restrict__ hs, const float* __restrict__ bw,
    float* __restrict__ bt)
{
    __shared__ float sh[ND];
    __shared__ float part[16][17];
    const int m = blockIdx.x, tid = threadIdx.x;
    ((float4*)sh)[tid * 2]     = ((const float4*)(hs + (size_t)m * ND))[tid * 2];
    ((float4*)sh)[tid * 2 + 1] = ((const float4*)(hs + (size_t)m * ND))[tid * 2 + 1];
    __syncthreads();
    const int h = tid & 15, seg = tid >> 4;
    float p = 0.f;
#pragma unroll 8
    for (int j = 0; j < 128; j++)
        p += sh[seg * 128 + j] * bw[(size_t)(seg * 128 + j) * 16 + h];
    part[seg][h] = p;
    __syncthreads();
    if (tid < 16) {
        float s = 0.f;
#pragma unroll
        for (int i = 0; i < 16; i++) s += part[i][tid];
        const int t = m & (NT - 1), b = m >> 12;
        bt[(size_t)(b * NH + tid) * NT + t] = sigmoidf_(s);
    }
}

// ---------------------------------------------------------------------------
// Phase 1 (parallel over 8192 chunks). Round 9: round-8 layouts + XOR bank
// swizzles (both-sides with scan4's LDS reads):
//   P'/q~: short off = row*128 + ((pair layout) ^ ((row&7)<<3))
//   khat : short off = ((krow-pair layout) ^ ((krow&7)<<3)) within 2048-blk
//   Bd   : float idx = ((si*16+sj) ^ ((si&7)<<2)) within 256-blk
//   vv (transposed), eCB: unchanged.
// ---------------------------------------------------------------------------
__global__ __launch_bounds__(256) void kda_prep(
    unsigned short* __restrict__ qn, unsigned short* __restrict__ kn,
    unsigned short* __restrict__ vv, unsigned short* __restrict__ gkh,
    const float* __restrict__ bt,
    float* __restrict__ BdB, float* __restrict__ eCB)
{
    __shared__ float cL[16][132];
    __shared__ float kL[16][132];
    __shared__ float qL[16][132];
    __shared__ float kapL[16][132];
    __shared__ float AbL[16][16];
    __shared__ float bL[16];
    __shared__ float sx[16][264];

    const int blk = blockIdx.x;
    const int bh  = blk >> 8;
    const int cc  = blk & 255;
    const int tid = threadIdx.x;
    const size_t ebase  = ((size_t)bh * NT + cc * 16) * 128;
    const size_t chbase = (size_t)bh * NCH + cc;

    if (tid < 16) bL[tid] = bt[(size_t)bh * NT + cc * 16 + tid];

    if (tid < 128) {
        const int d = tid;
        float c = 0.f;
#pragma unroll
        for (int i = 0; i < 16; i++) {
            float g = (float)(((const _Float16*)gkh)[ebase + i * 128 + d]);
            c += g;
            cL[i][d] = c;
            float kv = bf2f(kn[ebase + i * 128 + d]);
            float qv = bf2f(qn[ebase + i * 128 + d]);
            kL[i][d] = kv; qL[i][d] = qv;
            kapL[i][d] = kv * expf(c);
        }
        eCB[chbase * 128 + d] = expf(c);
    }
    __syncthreads();

    // khat^T write, pair-interleaved + XOR swizzle
    if (tid < 128) {
        const int d = tid;
        const int t = d >> 4, rr = d & 15;
        const int sw = (rr & 7) << 3;
        const float clast = cL[15][d];
        unsigned u[8];
#pragma unroll
        for (int e = 0; e < 8; e++) {
            float v0 = bL[2 * e]     * kL[2 * e][d]     * expf(clast - cL[2 * e][d]);
            float v1 = bL[2 * e + 1] * kL[2 * e + 1][d] * expf(clast - cL[2 * e + 1][d]);
            u[e] = pack2(v0, v1);
        }
        const unsigned bs = ((t >> 1) * 16 + rr) * 32 + (t & 1) * 4;
        unsigned short* base = gkh + chbase * 2048;
        *(uint2*)(base + ((bs +  0) ^ sw)) = make_uint2(u[0], u[1]);
        *(uint2*)(base + ((bs +  8) ^ sw)) = make_uint2(u[2], u[3]);
        *(uint2*)(base + ((bs + 16) ^ sw)) = make_uint2(u[4], u[5]);
        *(uint2*)(base + ((bs + 24) ^ sw)) = make_uint2(u[6], u[7]);
    }

    const int si = tid >> 4, sj = tid & 15;
    float aAcc = 0.f, bAcc = 0.f;
    if (si >= sj) {
        for (int d4 = 0; d4 < 128; d4 += 4) {
            float4 ci = *(const float4*)&cL[si][d4];
            float4 cj = *(const float4*)&cL[sj][d4];
            float4 ki = *(const float4*)&kL[si][d4];
            float4 kj = *(const float4*)&kL[sj][d4];
            float4 qi = *(const float4*)&qL[si][d4];
            float w;
            w = expf(ci.x - cj.x); aAcc += ki.x * kj.x * w; bAcc += qi.x * kj.x * w;
            w = expf(ci.y - cj.y); aAcc += ki.y * kj.y * w; bAcc += qi.y * kj.y * w;
            w = expf(ci.z - cj.z); aAcc += ki.z * kj.z * w; bAcc += qi.z * kj.z * w;
            w = expf(ci.w - cj.w); aAcc += ki.w * kj.w * w; bAcc += qi.w * kj.w * w;
        }
    }
    if (si > sj) AbL[si][sj] = aAcc * bL[sj];
    BdB[chbase * 256 + ((si * 16 + sj) ^ ((si & 7) << 2))] = bAcc * bL[sj];
    __syncthreads();

    // solve M x = r, M = I + tril(Ab): cols 0..127 kappa, 128..255 v
    {
        const int col = tid;
        float x[16];
#pragma unroll
        for (int i = 0; i < 16; i++)
            x[i] = (col < 128) ? kapL[i][col]
                               : bf2f(vv[ebase + (size_t)i * 128 + (col - 128)]);
#pragma unroll
        for (int i = 1; i < 16; i++) {
            float s = x[i];
#pragma unroll
            for (int l = 0; l < 15; l++)
                if (l < i) s -= AbL[i][l] * x[l];
            x[i] = s;
        }
#pragma unroll
        for (int i = 0; i < 16; i++) sx[i][col] = x[i];
    }
    __syncthreads();

    // P' / q~ writes, pair-interleaved + XOR swizzle
    {
        const int row = tid >> 4, q16 = tid & 15;
        const int d0 = q16 * 8;
        const int t  = q16 >> 1;
        const int pos0 = (t >> 1) * 32 + (t & 1) * 4 + (q16 & 1) * 16;
        const int sw = (row & 7) << 3;
        const int oA = pos0 ^ sw;
        const int oB = (pos0 + 8) ^ sw;
        unsigned pu[4], qu[4];
#pragma unroll
        for (int e = 0; e < 4; e++) {
            pu[e] = pack2(-sx[row][d0 + 2 * e], -sx[row][d0 + 2 * e + 1]);
            qu[e] = pack2(qL[row][d0 + 2 * e]     * expf(cL[row][d0 + 2 * e]),
                          qL[row][d0 + 2 * e + 1] * expf(cL[row][d0 + 2 * e + 1]));
        }
        unsigned short* kb = kn + ebase + (size_t)row * 128;
        unsigned short* qb = qn + ebase + (size_t)row * 128;
        *(uint2*)(kb + oA) = make_uint2(pu[0], pu[1]);
        *(uint2*)(kb + oB) = make_uint2(pu[2], pu[3]);
        *(uint2*)(qb + oA) = make_uint2(qu[0], qu[1]);
        *(uint2*)(qb + oB) = make_uint2(qu[2], qu[3]);
    }
    // V' transposed write (unchanged)
    if (tid < 128) {
        const int c = tid;
        unsigned u2[8];
#pragma unroll
        for (int e = 0; e < 8; e++)
            u2[e] = pack2(sx[2 * e][128 + c], sx[2 * e + 1][128 + c]);
        unsigned short* vb = vv + ebase + (size_t)c * 16;
        *(uint4*)(vb)     = make_uint4(u2[0], u2[1], u2[2], u2[3]);
        *(uint4*)(vb + 8) = make_uint4(u2[4], u2[5], u2[6], u2[7]);
    }
}

// ---------------------------------------------------------------------------
// Phase 2 scan4: 256 blocks (bh,vg) x 1 wave. Async chunk pipeline:
// issue chunk cc+1 into LDS buf^1 (17 global_load_lds), s_waitcnt vmcnt(17),
// compute chunk cc from LDS buf (XOR-swizzled ds_read_b128). No barriers.
// ---------------------------------------------------------------------------
__global__ __launch_bounds__(64) void kda_scan4(
    const unsigned short* __restrict__ qn, const unsigned short* __restrict__ kn,
    const unsigned short* __restrict__ vv, const unsigned short* __restrict__ khat,
    const float* __restrict__ BdB, const float* __restrict__ eCB,
    float* __restrict__ osc)
{
    __shared__ unsigned short Pl[2][2048];
    __shared__ unsigned short Ql[2][2048];
    __shared__ unsigned short KHl[2][2048];
    __shared__ unsigned short Vl[2][256];
    __shared__ float eCl[2][128];
    __shared__ float Bdl[2][256];

    const int bh = blockIdx.x & 31;   // same bh -> same XCD (32 % 8 == 0)
    const int vg = blockIdx.x >> 5;
    const int lane = threadIdx.x;
    const int r16 = lane & 15, h4 = lane >> 4;
    const int bb = bh >> 4, hh = bh & 15;
    const int sw = (r16 & 7) << 3;    // short-offset XOR (bytes: <<4)

    f32x4 Sm[8];
    short4v Shi[8];
    const short4v z4 = {0, 0, 0, 0};
#pragma unroll
    for (int t = 0; t < 8; t++) { Sm[t] = (f32x4){0.f, 0.f, 0.f, 0.f}; Shi[t] = z4; }

    auto issue = [&](int cc, int buf) {
        const size_t ebase = ((size_t)bh * NT + cc * 16) * 128;
        const size_t chb = (size_t)bh * NCH + cc;
#pragma unroll
        for (int i = 0; i < 4; i++) {
            gl2lds16(kn + ebase + i * 512 + lane * 8, &Pl[buf][i * 512]);
            gl2lds16(qn + ebase + i * 512 + lane * 8, &Ql[buf][i * 512]);
            gl2lds16(khat + chb * 2048 + i * 512 + lane * 8, &KHl[buf][i * 512]);
        }
#pragma unroll
        for (int j = 0; j < 2; j++) {
            gl2lds4((const char*)(vv + ebase + (size_t)vg * 256) + j * 256 + lane * 4,
                    &Vl[buf][j * 128]);
            gl2lds4((const char*)(eCB + chb * 128) + j * 256 + lane * 4,
                    &eCl[buf][j * 64]);
        }
        gl2lds16((const char*)(BdB + chb * 256) + lane * 16, &Bdl[buf][0]);
    };

    issue(0, 0);
    for (int cc = 0; cc < NCH; ++cc) {
        const int cur = cc & 1;
        if (cc + 1 < NCH) {
            issue(cc + 1, cur ^ 1);
            asm volatile("s_waitcnt vmcnt(17)" ::: "memory");
        } else {
            asm volatile("s_waitcnt vmcnt(0)" ::: "memory");
        }
        __builtin_amdgcn_sched_barrier(0);

        const unsigned short* Pb  = &Pl[cur][0];
        const unsigned short* Qb  = &Ql[cur][0];
        const unsigned short* KHb = &KHl[cur][0];

        short8 Pp[4], Qp[4], KHp[4];
#pragma unroll
        for (int m = 0; m < 4; m++) {
            const int po = r16 * 128 + ((m * 32 + h4 * 8) ^ sw);
            Pp[m]  = *(const short8*)&Pb[po];
            Qp[m]  = *(const short8*)&Qb[po];
            KHp[m] = *(const short8*)&KHb[((m * 16 + r16) * 32 + h4 * 8) ^ sw];
        }
        short4v vvt = *(const short4v*)&Vl[cur][r16 * 16 + h4 * 4];
        float4 eCt[8];
#pragma unroll
        for (int t = 0; t < 8; t++)
            eCt[t] = *(const float4*)&eCl[cur][t * 16 + h4 * 4];
        float4 bd4 = *(const float4*)&Bdl[cur][(r16 * 16 + h4 * 4) ^ ((r16 & 7) << 2)];
        short4v bdf;
        bdf[0] = (short)f2bf(bd4.x); bdf[1] = (short)f2bf(bd4.y);
        bdf[2] = (short)f2bf(bd4.z); bdf[3] = (short)f2bf(bd4.w);

        // err / o chains (4 independent chains of 4 MFMAs)
        f32x4 e0, e1 = {0.f, 0.f, 0.f, 0.f};
        f32x4 o0 = {0.f, 0.f, 0.f, 0.f}, o1 = {0.f, 0.f, 0.f, 0.f};
        e0[0] = bf2f((unsigned short)vvt[0]); e0[1] = bf2f((unsigned short)vvt[1]);
        e0[2] = bf2f((unsigned short)vvt[2]); e0[3] = bf2f((unsigned short)vvt[3]);
#pragma unroll
        for (int m = 0; m < 4; m++) {
            e0 = mfma16(lo4(Pp[m]), Shi[2 * m],     e0);
            e1 = mfma16(hi4(Pp[m]), Shi[2 * m + 1], e1);
            o0 = mfma16(lo4(Qp[m]), Shi[2 * m],     o0);
            o1 = mfma16(hi4(Qp[m]), Shi[2 * m + 1], o1);
        }
        f32x4 accE, accO;
        accE[0] = e0[0] + e1[0]; accE[1] = e0[1] + e1[1];
        accE[2] = e0[2] + e1[2]; accE[3] = e0[3] + e1[3];
        accO[0] = o0[0] + o1[0]; accO[1] = o0[1] + o1[1];
        accO[2] = o0[2] + o1[2]; accO[3] = o0[3] + o1[3];

        short4v ef;
        ef[0] = (short)f2bf(accE[0]); ef[1] = (short)f2bf(accE[1]);
        ef[2] = (short)f2bf(accE[2]); ef[3] = (short)f2bf(accE[3]);
        accO = mfma16(bdf, ef, accO);

        // state update (8 independent MFMAs)
#pragma unroll
        for (int t = 0; t < 8; t++) {
            const short4v khf = (t & 1) ? hi4(KHp[t >> 1]) : lo4(KHp[t >> 1]);
            f32x4 ns;
            ns[0] = eCt[t].x * Sm[t][0];
            ns[1] = eCt[t].y * Sm[t][1];
            ns[2] = eCt[t].z * Sm[t][2];
            ns[3] = eCt[t].w * Sm[t][3];
            ns = mfma16(khf, ef, ns);
            Sm[t] = ns;
            short4v nh;
            nh[0] = (short)f2bf(ns[0]); nh[1] = (short)f2bf(ns[1]);
            nh[2] = (short)f2bf(ns[2]); nh[3] = (short)f2bf(ns[3]);
            Shi[t] = nh;
        }

        // o write: rows i = h4*4+r, col hh*128 + vg*16 + r16
        const size_t obase = ((size_t)bb * NT + cc * 16) * ND + hh * 128 + vg * 16 + r16;
#pragma unroll
        for (int r = 0; r < 4; r++)
            osc[obase + (size_t)(h4 * 4 + r) * ND] = accO[r];
    }
}

// ---------------------------------------------------------------------------
// Gated RMSNorm epilogue (unchanged).
// ---------------------------------------------------------------------------
__global__ __launch_bounds__(256) void gate_k(
    const float* __restrict__ osc, const unsigned short* __restrict__ gateb,
    const float* __restrict__ gb2, const float* __restrict__ onw,
    unsigned short* __restrict__ ogb)
{
    const int m = blockIdx.x, tid = threadIdx.x;
    const int hd = tid * 8, d0 = hd & 127;
    const float* op = osc + (size_t)m * ND + hd;
    float4 o0 = *(const float4*)op, o1 = *(const float4*)(op + 4);
    float ssum = o0.x * o0.x + o0.y * o0.y + o0.z * o0.z + o0.w * o0.w +
                 o1.x * o1.x + o1.y * o1.y + o1.z * o1.z + o1.w * o1.w;
    ssum = reduce16f(ssum);
    const float r = rsqrtf(ssum * (1.0f / 128.0f) + 1e-5f);
    uint4 gu = *(const uint4*)(gateb + (size_t)m * ND + hd);
    float4 gl = bflo(gu), gh = bfhi(gu);
    float4 b0 = *(const float4*)&gb2[hd], b1 = *(const float4*)&gb2[hd + 4];
    float4 w0 = *(const float4*)&onw[d0], w1 = *(const float4*)&onw[d0 + 4];
    float res[8];
    res[0] = o0.x * r * w0.x * sigmoidf_(gl.x + b0.x);
    res[1] = o0.y * r * w0.y * sigmoidf_(gl.y + b0.y);
    res[2] = o0.z * r * w0.z * sigmoidf_(gl.z + b0.z);
    res[3] = o0.w * r * w0.w * sigmoidf_(gl.w + b0.w);
    res[4] = o1.x * r * w1.x * sigmoidf_(gh.x + b1.x);
    res[5] = o1.y * r * w1.y * sigmoidf_(gh.y + b1.y);
    res[6] = o1.z * r * w1.z * sigmoidf_(gh.z + b1.z);
    res[7] = o1.w * r * w1.w * sigmoidf_(gh.w + b1.w);
    uint4 pk;
    pk.x = pack2(res[0], res[1]); pk.y = pack2(res[2], res[3]);
    pk.z = pack2(res[4], res[5]); pk.w = pack2(res[6], res[7]);
    *(uint4*)(ogb + (size_t)m * ND + hd) = pk;
}

__global__ void diag_fill(float* out, float val, int n) {
    for (int i = blockIdx.x * blockDim.x + threadIdx.x; i < n; i += gridDim.x * blockDim.x)
        out[i] = val;
}

// ---------------------------------------------------------------------------
extern "C" void kernel_launch(void* const* d_in, const int* in_sizes, int n_in,
                              void* d_out, int out_size, void* d_ws, size_t ws_size,
                              hipStream_t stream)
{
    const float* hs    = (const float*)d_in[0];
    const float* q_w   = (const float*)d_in[1];
    const float* k_w   = (const float*)d_in[2];
    const float* v_w   = (const float*)d_in[3];
    const float* qcw   = (const float*)d_in[4];
    const float* kcw   = (const float*)d_in[5];
    const float* vcw   = (const float*)d_in[6];
    const float* f_w1  = (const float*)d_in[7];
    const float* f_w2  = (const float*)d_in[8];
    const float* b_w   = (const float*)d_in[9];
    const float* A_log = (const float*)d_in[10];
    const float* dt_b  = (const float*)d_in[11];
    const float* g_w1  = (const float*)d_in[12];
    const float* g_w2  = (const float*)d_in[13];
    const float* g_b2  = (const float*)d_in[14];
    const float* onw   = (const float*)d_in[15];
    const float* o_w   = (const float*)d_in[16];
    float* out = (float*)d_out;

    // ---- workspace layout (bytes), peak ~187 MB ----------------------------
    const size_t SEQ = (size_t)BHN * NT;           // 131072
    const size_t BF  = SEQ * 128 * 2;              // bf16 stream: 32 MiB
    char* wsb = (char*)d_ws;
    size_t off = 0;
    unsigned short* qn   = (unsigned short*)(wsb + off); off += BF;
    unsigned short* kn   = (unsigned short*)(wsb + off); off += BF;
    unsigned short* vv   = (unsigned short*)(wsb + off); off += BF;  // ogb post-scan
    unsigned short* dc   = (unsigned short*)(wsb + off); off += BF;  // gk fp16 -> khat
    unsigned short* P1   = (unsigned short*)(wsb + off); off += (size_t)MROWS * ND * 2;
    unsigned short* WT   = (unsigned short*)(wsb + off); off += (size_t)ND * ND * 2;
    unsigned short* fw1t = (unsigned short*)(wsb + off); off += (size_t)DK * ND * 2;
    unsigned short* fw2t = (unsigned short*)(wsb + off); off += (size_t)ND * DK * 2;
    unsigned short* gw1t = (unsigned short*)(wsb + off); off += (size_t)DK * ND * 2;
    unsigned short* gw2t = (unsigned short*)(wsb + off); off += (size_t)ND * DK * 2;
    unsigned short* f1b  = (unsigned short*)(wsb + off); off += (size_t)MROWS * DK * 2;
    unsigned short* g1b  = (unsigned short*)(wsb + off); off += (size_t)MROWS * DK * 2;
    float* bt  = (float*)(wsb + off); off += SEQ * 4;
    float* BdB = (float*)(wsb + off); off += (size_t)BHN * NCH * 256 * 4;  // 8 MiB
    float* eCB = (float*)(wsb + off); off += (size_t)BHN * NCH * 128 * 4;  // 4 MiB
    unsigned short* ogb = vv;
    unsigned short* hsb = (unsigned short*)d_out;

    if (ws_size < off) {
        diag_fill<<<512, 256, 0, stream>>>(out, 1.0e6f + (float)(ws_size >> 20), out_size);
        return;
    }

    dim3 blk(256);
    auto g2 = [](int Md, int Nd) { return dim3((unsigned)((Md >> 7) * (Nd >> 7))); };
    auto gt = [](int Kd, int Nd) { return dim3((unsigned)((Kd >> 6) * (Nd >> 6))); };

    // 0. hs -> bf16 (staged in d_out; consumed before scan4 overwrites)
    f2bf_k<<<(MROWS * ND / 8 + 255) / 256, blk, 0, stream>>>(hs, hsb, MROWS * ND / 8);

    // 1. q/k/v projections + conv/silu(/l2norm)
    wtrans<<<gt(ND, ND), blk, 0, stream>>>(q_w, WT, ND, ND);
    gemm_bf16<1><<<g2(MROWS, ND), blk, 0, stream>>>(hsb, WT, P1, MROWS, ND, ND);
    conv_silu<2><<<MROWS, blk, 0, stream>>>(P1, qcw, qn);
    wtrans<<<gt(ND, ND), blk, 0, stream>>>(k_w, WT, ND, ND);
    gemm_bf16<1><<<g2(MROWS, ND), blk, 0, stream>>>(hsb, WT, P1, MROWS, ND, ND);
    conv_silu<1><<<MROWS, blk, 0, stream>>>(P1, kcw, kn);
    wtrans<<<gt(ND, ND), blk, 0, stream>>>(v_w, WT, ND, ND);
    gemm_bf16<1><<<g2(MROWS, ND), blk, 0, stream>>>(hsb, WT, P1, MROWS, ND, ND);
    conv_silu<0><<<MROWS, blk, 0, stream>>>(P1, vcw, vv);

    // 2. decay path -> gk fp16
    wtrans<<<gt(ND, DK), blk, 0, stream>>>(f_w1, fw1t, ND, DK);
    gemm_bf16<1><<<g2(MROWS, DK), blk, 0, stream>>>(hsb, fw1t, f1b, MROWS, DK, ND);
    wtrans<<<gt(DK, ND), blk, 0, stream>>>(f_w2, fw2t, DK, ND);
    gemm_bf16<1><<<g2(MROWS, ND), blk, 0, stream>>>(f1b, fw2t, P1, MROWS, ND, DK);
    gk_k<<<MROWS, blk, 0, stream>>>(P1, A_log, dt_b, (_Float16*)dc);

    // 3. output gate preact -> P1 (survives scan, consumed by gate_k)
    wtrans<<<gt(ND, DK), blk, 0, stream>>>(g_w1, gw1t, ND, DK);
    gemm_bf16<1><<<g2(MROWS, DK), blk, 0, stream>>>(hsb, gw1t, g1b, MROWS, DK, ND);
    wtrans<<<gt(DK, ND), blk, 0, stream>>>(g_w2, gw2t, DK, ND);
    gemm_bf16<1><<<g2(MROWS, ND), blk, 0, stream>>>(g1b, gw2t, P1, MROWS, ND, DK);

    // 4. beta
    beta_k<<<MROWS, blk, 0, stream>>>(hs, b_w, bt);

    // 5. chunked delta rule: prep (parallel) + scan4 (serial chunks, async LDS)
    kda_prep<<<BHN * NCH, blk, 0, stream>>>(qn, kn, vv, dc, bt, BdB, eCB);
    kda_scan4<<<BHN * 8, 64, 0, stream>>>(qn, kn, vv, dc, BdB, eCB, out);

    // 6. gated RMSNorm -> ogb bf16 (aliases vv)
    gate_k<<<MROWS, blk, 0, stream>>>(out, P1, g_b2, onw, ogb);

    // 7. final projection
    wtrans<<<gt(ND, ND), blk, 0, stream>>>(o_w, WT, ND, ND);
    gemm_bf16<0><<<g2(MROWS, ND), blk, 0, stream>>>(ogb, WT, out, MROWS, ND, ND);
}